// Round 5
// baseline (71.933 us; speedup 1.0000x reference)
//
#include <hip/hip_runtime.h>

typedef unsigned short u16;
typedef unsigned int u32;
typedef __attribute__((ext_vector_type(8))) __bf16 bf16x8;
typedef __attribute__((ext_vector_type(4))) float f32x4;

#define NB 4
#define SEQ 2048
#define DIM 512
#define NH 8
#define HD 64
#define OV 32
#define PD 2112

#define PACK_N (NB * PD * (DIM / 4))
#define WIN_N (3 * DIM * DIM / 4)
#define WOUT_N (DIM * DIM / 4)

// async global->LDS, 16B per lane, wave-uniform LDS base + lane*16
#define GLL(g, l)                                                  \
  __builtin_amdgcn_global_load_lds(                                \
      (const __attribute__((address_space(1))) void*)(g),          \
      (__attribute__((address_space(3))) void*)(l), 16, 0, 0)

__device__ __forceinline__ u16 f2bf(float f) {
  union { float f; u32 u; } x; x.f = f;
  u32 r = x.u + 0x7fffu + ((x.u >> 16) & 1u);
  return (u16)(r >> 16);
}

// ---------------- fused prep ----------------
__global__ void k_prep(const float* __restrict__ begin,
                       const float* __restrict__ mainp,
                       const float* __restrict__ endp,
                       const float* __restrict__ w_in_f,
                       const float* __restrict__ w_out_f,
                       u16* __restrict__ pad,
                       u16* __restrict__ w_in,
                       u16* __restrict__ w_out) {
  int i = blockIdx.x * 256 + threadIdx.x;
  const float* src;
  u16* dst;
  if (i < PACK_N) {
    int d4 = (i & 127) * 4;
    int p = (i >> 7) % PD;
    int b = i / (PD * (DIM / 4));
    if (p < OV)            src = begin + ((size_t)(b * OV + p)) * DIM + d4;
    else if (p < OV + SEQ) src = mainp + ((size_t)(b * SEQ + (p - OV))) * DIM + d4;
    else                   src = endp + ((size_t)(b * OV + (p - OV - SEQ))) * DIM + d4;
    dst = pad + (size_t)i * 4;
  } else if (i < PACK_N + WIN_N) {
    int j = i - PACK_N;
    src = w_in_f + (size_t)j * 4;
    dst = w_in + (size_t)j * 4;
  } else if (i < PACK_N + WIN_N + WOUT_N) {
    int j = i - PACK_N - WIN_N;
    src = w_out_f + (size_t)j * 4;
    dst = w_out + (size_t)j * 4;
  } else {
    return;
  }
  float4 v = *(const float4*)src;
  u32 lo = (u32)f2bf(v.x) | ((u32)f2bf(v.y) << 16);
  u32 hi = (u32)f2bf(v.z) | ((u32)f2bf(v.w) << 16);
  *(uint2*)dst = make_uint2(lo, hi);
}

// ---------------- GEMM mainloop: 128x128 tile, BK=64, single-buffer m97 structure ----
// A [M][512], Bw [N][512] bf16 K-major. 256 thr = 4 waves (2x2), 64x64/wave.
// LDS: As[128][64] + Bs[128][64] linear, K-granule swizzle g^=(row&7) (pre-swizzled
// on the global source, applied on the ds_read address).

__device__ __forceinline__ void gemm_loop_sb(const u16* __restrict__ A,
                                             const u16* __restrict__ Bw,
                                             int tm0, int tn0,
                                             u16* __restrict__ As, u16* __restrict__ Bs,
                                             f32x4 acc[4][4]) {
  const int tid = threadIdx.x;
  const int lane = tid & 63;
  const int w = tid >> 6;
  const int rr = lane & 15, g = lane >> 4;
  const int wm = (w >> 1) * 64, wn = (w & 1) * 64;
  const int srow = tid >> 3;                 // 0..31 (staged row within 32-row sweep)
  const int lg = (tid & 7) ^ (srow & 7);     // pre-swizzled source granule
  const u16* gA = A + (size_t)(tm0 + srow) * 512 + lg * 8;
  const u16* gB = Bw + (size_t)(tn0 + srow) * 512 + lg * 8;
  char* lA = (char*)As + w * 1024;
  char* lB = (char*)Bs + w * 1024;
#pragma unroll 1
  for (int t = 0; t < 8; ++t) {
#pragma unroll
    for (int j = 0; j < 4; ++j) {
      GLL(gA + (size_t)j * 32 * 512 + t * 64, lA + j * 4096);
      GLL(gB + (size_t)j * 32 * 512 + t * 64, lB + j * 4096);
    }
    __syncthreads();
    bf16x8 af[4][2], bfr[4][2];
#pragma unroll
    for (int f = 0; f < 4; ++f) {
#pragma unroll
      for (int ks = 0; ks < 2; ++ks) {
        int ra = wm + f * 16 + rr;
        int rb = wn + f * 16 + rr;
        af[f][ks] = *(const bf16x8*)&As[ra * 64 + (((ks * 4 + g) ^ (ra & 7)) << 3)];
        bfr[f][ks] = *(const bf16x8*)&Bs[rb * 64 + (((ks * 4 + g) ^ (rb & 7)) << 3)];
      }
    }
#pragma unroll
    for (int ks = 0; ks < 2; ++ks)
#pragma unroll
      for (int fm = 0; fm < 4; ++fm)
#pragma unroll
        for (int fn = 0; fn < 4; ++fn)
          acc[fm][fn] = __builtin_amdgcn_mfma_f32_16x16x32_bf16(af[fm][ks], bfr[fn][ks], acc[fm][fn], 0, 0, 0);
    __syncthreads();
  }
}

// QKV GEMM: M=8448, N=1536. LDS-staged coalesced epilogue.
// q,k head-major [p][d]; v transposed head-major [d][p].
__global__ __launch_bounds__(256) void k_gemm_qkv(const u16* __restrict__ A,
                                                  const u16* __restrict__ Bw,
                                                  const float* __restrict__ bias,
                                                  u16* __restrict__ qh,
                                                  u16* __restrict__ kh,
                                                  u16* __restrict__ vt) {
  __shared__ __align__(16) u16 smem[17408];   // mainloop: As[8192]+Bs[8192]; epilogue: C[128][136]
  const int bx = blockIdx.x;
  const int tm0 = (bx / 12) * 128, tn0 = (bx % 12) * 128;
  f32x4 acc[4][4] = {};
  gemm_loop_sb(A, Bw, tm0, tn0, smem, smem + 8192, acc);

  const int tid = threadIdx.x, lane = tid & 63, wv = tid >> 6;
  const int rr = lane & 15, g = lane >> 4;
  const int wm = (wv >> 1) * 64, wn = (wv & 1) * 64;
  // acc (+bias) -> LDS C tile (loop ended with __syncthreads, smem free)
#pragma unroll
  for (int fm = 0; fm < 4; ++fm)
#pragma unroll
    for (int fn = 0; fn < 4; ++fn) {
      float bb = bias[tn0 + wn + fn * 16 + rr];
#pragma unroll
      for (int r = 0; r < 4; ++r)
        smem[(wm + fm * 16 + g * 4 + r) * 136 + wn + fn * 16 + rr] = f2bf(acc[fm][fn][r] + bb);
    }
  __syncthreads();

  const int reg = tn0 >> 9;                   // block-uniform: 0=q, 1=k, 2=v
  if (reg < 2) {
    // coalesced row-major readout: 2 threads/row, 128 B contiguous each
    int r2 = tid >> 1, hf = tid & 1;
    int grow = tm0 + r2;
    int b = grow / PD, p = grow - b * PD;
    int cb = (tn0 & 511) + hf * 64;
    int h = cb >> 6;
    const uint4* s = (const uint4*)&smem[r2 * 136 + hf * 64];
    u16* dst = nullptr;
    if (reg == 1) dst = kh + (((size_t)(b * NH + h)) * PD + p) * HD;
    else if (p >= OV && p < OV + SEQ) dst = qh + (((size_t)(b * NH + h)) * SEQ + (p - OV)) * HD;
    if (dst) {
#pragma unroll
      for (int i = 0; i < 8; ++i) ((uint4*)dst)[i] = s[i];
    }
  } else {
    // v transpose readout: thread = one column, 8 p's per 16B store
    int col = tid >> 1;
    int rb = (tid & 1) * 64;
    int c = (tn0 & 511) + col;
    int h = c >> 6, d = c & 63;
#pragma unroll
    for (int ch = 0; ch < 8; ++ch) {
      int grow = tm0 + rb + ch * 8;           // 8-aligned; PD%8==0 -> no b straddle
      int b = grow / PD, p0 = grow - b * PD;
      u32 w4[4];
#pragma unroll
      for (int i = 0; i < 4; ++i) {
        u32 lo = smem[(rb + ch * 8 + 2 * i) * 136 + col];
        u32 hi = smem[(rb + ch * 8 + 2 * i + 1) * 136 + col];
        w4[i] = lo | (hi << 16);
      }
      *(uint4*)&vt[(((size_t)(b * NH + h)) * HD + d) * PD + p0] = *(uint4*)w4;
    }
  }
}

// out-proj GEMM: M=8192, N=512 -> out[:,512:1024] fp32; fused main passthrough
__global__ __launch_bounds__(256) void k_gemm_oproj(const u16* __restrict__ A,
                                                    const u16* __restrict__ Bw,
                                                    const float* __restrict__ bias,
                                                    const float* __restrict__ mainp,
                                                    float* __restrict__ out) {
  __shared__ __align__(16) u16 smem[16384];
  int bx = blockIdx.x;
  int tm0 = (bx >> 2) * 128, tn0 = (bx & 3) * 128;
  for (int i = threadIdx.x; i < 4096; i += 256) {
    int r = i >> 5, c4 = (i & 31) * 4;
    *(float4*)&out[(size_t)(tm0 + r) * 1024 + tn0 + c4] =
        *(const float4*)&mainp[(size_t)(tm0 + r) * 512 + tn0 + c4];
  }
  f32x4 acc[4][4] = {};
  gemm_loop_sb(A, Bw, tm0, tn0, smem, smem + 8192, acc);
  int lane = threadIdx.x & 63, wv = threadIdx.x >> 6;
  int rr = lane & 15, g = lane >> 4;
  int wm = (wv >> 1) * 64, wn = (wv & 1) * 64;
#pragma unroll
  for (int fm = 0; fm < 4; ++fm)
#pragma unroll
    for (int fn = 0; fn < 4; ++fn) {
      int j = tn0 + wn + fn * 16 + rr;
      float bb = bias[j];
#pragma unroll
      for (int r = 0; r < 4; ++r) {
        int row = tm0 + wm + fm * 16 + g * 4 + r;
        out[(size_t)row * 1024 + 512 + j] = acc[fm][fn][r] + bb;
      }
    }
}

// ---------------- MFMA banded attention (unchanged) ----------------
__device__ __forceinline__ int pswz(int slot, int key) {
  return (slot < 8) ? (slot ^ (key & 7)) : ((slot & 12) | ((slot ^ (key & 3)) & 3));
}

__global__ __launch_bounds__(256) void k_attn(const u16* __restrict__ qh,
                                              const u16* __restrict__ kh,
                                              const u16* __restrict__ vt,
                                              u16* __restrict__ ob) {
  __shared__ __align__(16) u16 Ks[128 * 64];
  __shared__ __align__(16) u16 Vs[64 * 128];
  __shared__ __align__(16) u16 Qs[64 * 64];
  __shared__ __align__(16) u16 Ps[4 * 16 * 96];
  const int tid = threadIdx.x;
  const int lane = tid & 63;
  const int wq = tid >> 6;
  const int g = lane >> 4, qi = lane & 15;
  const int bx = blockIdx.x;
  const int tile = bx & 31, h = (bx >> 5) & 7, b = bx >> 8;
  const int l0 = tile * 64;
  const size_t bh = (size_t)(b * NH + h);

  {
    const u16* kg = kh + (bh * PD + l0) * HD;
#pragma unroll
    for (int i = 0; i < 4; ++i) {
      int c = tid + 256 * i;
      int row = c >> 3, slot = c & 7;
      *(uint4*)&Ks[row * 64 + ((slot ^ (row & 7)) << 3)] =
          *(const uint4*)&kg[(size_t)row * HD + slot * 8];
    }
    const u16* vg = vt + bh * HD * PD + l0;
#pragma unroll
    for (int i = 0; i < 4; ++i) {
      int c = tid + 256 * i;
      int d = c >> 4, slot = c & 15;
      *(uint4*)&Vs[d * 128 + ((slot ^ (d & 15)) << 3)] =
          *(const uint4*)&vg[(size_t)d * PD + slot * 8];
    }
    const u16* qg = qh + (bh * SEQ + l0) * HD;
#pragma unroll
    for (int i = 0; i < 2; ++i) {
      int c = tid + 256 * i;
      int row = c >> 3, slot = c & 7;
      *(uint4*)&Qs[row * 64 + ((slot ^ (row & 7)) << 3)] =
          *(const uint4*)&qg[(size_t)row * HD + slot * 8];
    }
  }
  __syncthreads();

  bf16x8 bq[2];
  {
    int qrow = 16 * wq + qi;
#pragma unroll
    for (int ks = 0; ks < 2; ++ks)
      bq[ks] = *(const bf16x8*)&Qs[qrow * 64 + ((((g + 4 * ks)) ^ (qrow & 7)) << 3)];
  }
  f32x4 sa[5];
#pragma unroll
  for (int tt = 0; tt < 5; ++tt) { f32x4 z = {0.f, 0.f, 0.f, 0.f}; sa[tt] = z; }
#pragma unroll
  for (int tt = 0; tt < 5; ++tt) {
    int krow = 16 * (wq + tt) + qi;
#pragma unroll
    for (int ks = 0; ks < 2; ++ks) {
      bf16x8 ak = *(const bf16x8*)&Ks[krow * 64 + (((g + 4 * ks) ^ (krow & 7)) << 3)];
      sa[tt] = __builtin_amdgcn_mfma_f32_16x16x32_bf16(ak, bq[ks], sa[tt], 0, 0, 0);
    }
  }

  float m = -1e30f;
#pragma unroll
  for (int tt = 0; tt < 5; ++tt)
#pragma unroll
    for (int r = 0; r < 4; ++r) {
      int rel = 16 * tt + 4 * g + r - qi;
      bool val = (rel >= 0) && (rel <= 64) && (rel != 32) && ((rel & 1) == 0);
      if (val) m = fmaxf(m, sa[tt][r]);
    }
  m = fmaxf(m, __shfl_xor(m, 16));
  m = fmaxf(m, __shfl_xor(m, 32));
  float p[5][4];
  float sum = 0.f;
#pragma unroll
  for (int tt = 0; tt < 5; ++tt)
#pragma unroll
    for (int r = 0; r < 4; ++r) {
      int rel = 16 * tt + 4 * g + r - qi;
      bool val = (rel >= 0) && (rel <= 64) && (rel != 32) && ((rel & 1) == 0);
      p[tt][r] = val ? __expf((sa[tt][r] - m) * 0.125f) : 0.f;
      sum += p[tt][r];
    }
  sum += __shfl_xor(sum, 16);
  sum += __shfl_xor(sum, 32);
  float inv = 1.f / sum;

  {
    int prow = 16 * wq + qi;
    int colb = (wq & 1) << 4;
#pragma unroll
    for (int tt = 0; tt < 5; ++tt) {
#pragma unroll
      for (int pp = 0; pp < 2; ++pp) {
        int e = 4 * g + 2 * pp;
        int slot = ((colb + 16 * tt) >> 3) + (e >> 3);
        int swz = pswz(slot, qi);
        u32 w = (u32)f2bf(p[tt][2 * pp] * inv) | ((u32)f2bf(p[tt][2 * pp + 1] * inv) << 16);
        *(u32*)&Ps[prow * 96 + swz * 8 + (e & 7)] = w;
      }
    }
    int zslot = ((wq & 1) ? 0 : 10) + ((lane >> 4) & 1);
    int half = lane >> 5;
    int swz = pswz(zslot, qi);
    uint2 z2 = make_uint2(0u, 0u);
    *(uint2*)&Ps[(16 * wq + qi) * 96 + swz * 8 + half * 4] = z2;
  }
  __syncthreads();

  f32x4 oa[4];
#pragma unroll
  for (int dt = 0; dt < 4; ++dt) { f32x4 z = {0.f, 0.f, 0.f, 0.f}; oa[dt] = z; }
  int kbo = (wq >= 2) ? 1 : 0;
#pragma unroll
  for (int kt = 0; kt < 3; ++kt) {
    int slot = 4 * kt + g;
    int swz = pswz(slot, qi);
    bf16x8 pa = *(const bf16x8*)&Ps[(16 * wq + qi) * 96 + swz * 8];
    int sabs = 4 * (kt + kbo) + g;
#pragma unroll
    for (int dt = 0; dt < 4; ++dt) {
      int d = 16 * dt + qi;
      bf16x8 bv = *(const bf16x8*)&Vs[d * 128 + ((sabs ^ (d & 15)) << 3)];
      oa[dt] = __builtin_amdgcn_mfma_f32_16x16x32_bf16(pa, bv, oa[dt], 0, 0, 0);
    }
  }

  u16* og = ob + ((size_t)b * SEQ + l0 + 16 * wq) * DIM + h * HD;
#pragma unroll
  for (int dt = 0; dt < 4; ++dt)
#pragma unroll
    for (int r = 0; r < 4; ++r) {
      int qo = 4 * g + r;
      og[(size_t)qo * DIM + 16 * dt + qi] = f2bf(oa[dt][r]);
    }
}

extern "C" void kernel_launch(void* const* d_in, const int* in_sizes, int n_in,
                              void* d_out, int out_size, void* d_ws, size_t ws_size,
                              hipStream_t stream) {
  const float* begin = (const float*)d_in[0];
  const float* mainp = (const float*)d_in[1];
  const float* endp = (const float*)d_in[2];
  const float* w_in_f = (const float*)d_in[3];
  const float* b_in = (const float*)d_in[4];
  const float* w_out_f = (const float*)d_in[5];
  const float* b_out = (const float*)d_in[6];
  float* out = (float*)d_out;

  char* ws = (char*)d_ws;
  u16* pad_bf = (u16*)ws; ws += (size_t)NB * PD * DIM * 2;
  u16* w_in = (u16*)ws;   ws += (size_t)3 * DIM * DIM * 2;
  u16* w_out = (u16*)ws;  ws += (size_t)DIM * DIM * 2;
  u16* qhb = (u16*)ws;    ws += (size_t)NB * NH * SEQ * HD * 2;
  u16* khb = (u16*)ws;    ws += (size_t)NB * NH * PD * HD * 2;
  u16* vtb = (u16*)ws;    ws += (size_t)NB * NH * HD * PD * 2;
  u16* ob = (u16*)ws;     ws += (size_t)NB * SEQ * DIM * 2;

  k_prep<<<(PACK_N + WIN_N + WOUT_N + 255) / 256, 256, 0, stream>>>(
      begin, mainp, endp, w_in_f, w_out_f, pad_bf, w_in, w_out);
  k_gemm_qkv<<<66 * 12, 256, 0, stream>>>(pad_bf, w_in, b_in, qhb, khb, vtb);
  k_attn<<<NB * NH * (SEQ / 64), 256, 0, stream>>>(qhb, khb, vtb, ob);
  k_gemm_oproj<<<64 * 4, 256, 0, stream>>>(ob, w_out, b_out, mainp, out);
}